// Round 22
// baseline (236.386 us; speedup 1.0000x reference)
//
#include <hip/hip_runtime.h>
#include <math.h>

#define VNUM 50000
#define OUTF 128
#define NEDGE 1600000
#define EPSF 1e-7f

#define BFRAG_BLOCKS 64     // 16384 uint pairs / 256

#define CHUNK 2048          // edges per coarse block
#define NCB 49              // coarse bins: tidx>>10 (1024 vertices/bin)
#define COARSE_BLOCKS 782   // ceil(NEDGE/CHUNK)
#define BSTRIDE 36864       // fixed segment stride; mean 32768 + 23 sigma
#define NSUB 4              // sub-blocks per bin (R8: 8 = +6.5us; R10 coop = +35us; R15 LDS-fuse = +1300us)
#define FINE_BLOCKS (NCB * NSUB)   // 196
#define CONV_BLOCKS 782     // conversion blocks @1024 thr

typedef __attribute__((ext_vector_type(8))) short short8;
typedef __attribute__((ext_vector_type(4))) float v4f;

// ---------------------------------------------------------------------------
// bf16 helpers (RNE)
// ---------------------------------------------------------------------------
__device__ __forceinline__ unsigned short f2bf(float f) {
    union { float f; unsigned int u; } c; c.f = f;
    unsigned int u = c.u;
    return (unsigned short)((u + 0x7FFFu + ((u >> 16) & 1u)) >> 16);
}
__device__ __forceinline__ float bf16_lo(unsigned int p) {
    union { unsigned int u; float f; } c; c.u = p << 16; return c.f;
}
__device__ __forceinline__ float bf16_hi(unsigned int p) {
    union { unsigned int u; float f; } c; c.u = p & 0xFFFF0000u; return c.f;
}

__device__ __forceinline__ int wave_incl_scan(int v, int lane) {
#pragma unroll
    for (int off = 1; off < 64; off <<= 1) {
        const int o = __shfl_up(v, off, 64);
        if (lane >= off) v += o;
    }
    return v;
}

// ---------------------------------------------------------------------------
// prep: block 0 = ccursor init + offs[VNUM]; blocks 1..64 = B-fragment build.
// ---------------------------------------------------------------------------
__global__ __launch_bounds__(256) void prep_kernel(
    int* __restrict__ ccursor, int* __restrict__ offs,
    const float* __restrict__ loc_w, const float* __restrict__ std_w,
    unsigned int* bfrag)
{
    const int b = blockIdx.x, tid = threadIdx.x;
    if (b == 0) {
        if (tid < NCB) ccursor[tid] = tid * BSTRIDE;
        if (tid == 63) offs[VNUM] = NEDGE;
    } else {
        const int p = (b - 1) * 256 + tid; // 0..16383
        const int j2 = p & 3, lq = (p >> 2) & 63, ks = (p >> 8) & 3, ct = p >> 10;
        const int k = ks * 32 + (lq >> 4) * 8 + j2 * 2;
        const int n = ct * 16 + (lq & 15);
        const float* wsrc = (n >> 7) ? std_w : loc_w;
        const int c = n & 127;
        bfrag[p] = (unsigned)f2bf(wsrc[c * 128 + k]) |
                   ((unsigned)f2bf(wsrc[c * 128 + k + 1]) << 16);
    }
}

// ---------------------------------------------------------------------------
// coarse: 49 fixed-stride bin segments via LDS staging + bulk-reserved runs.
// 6-byte records (c8m uint / c8v ushort). R21: NT loads on the 4 read-once
// edge streams (keeps L2 for the c8 write window; pairs/vrepr16 lesson from
// R6 says NT only on UNREUSED streams — these qualify).
// ---------------------------------------------------------------------------
__global__ __launch_bounds__(256) void coarse_kernel(
    const int* __restrict__ sidx, const int* __restrict__ tidx,
    const float* __restrict__ enorm, const float* __restrict__ esgn,
    int* __restrict__ ccursor,
    unsigned int* __restrict__ c8m, unsigned short* __restrict__ c8v)
{
    __shared__ unsigned int   lrecm[CHUNK];   // 8 KB
    __shared__ unsigned short lrecv[CHUNK];   // 4 KB
    __shared__ int lcnt[4][NCB];
    __shared__ int lbase[4][NCB];
    __shared__ int loffs[NCB];
    __shared__ int grun[NCB];

    const int tid = threadIdx.x, lane = tid & 63, wv = tid >> 6;
    const int base = blockIdx.x * CHUNK;
    const int n = min(CHUNK, NEDGE - base);

    for (int i = tid; i < 4 * NCB; i += 256) (&lcnt[0][0])[i] = 0;
    __syncthreads();

    unsigned int rm[8];
    unsigned short rv[8];
#pragma unroll
    for (int j = 0; j < 8; ++j) {
        const int e = base + j * 256 + tid;
        if (e < NEDGE) {
            const int t = __builtin_nontemporal_load(tidx + e);
            const float w = __builtin_nontemporal_load(esgn + e) *
                            __builtin_nontemporal_load(enorm + e);
            rm[j] = ((unsigned)__builtin_nontemporal_load(sidx + e) << 16) |
                    (unsigned)f2bf(w);
            rv[j] = (unsigned short)t;
            atomicAdd(&lcnt[wv][t >> 10], 1);
        }
    }
    __syncthreads();

    if (tid < 64) {
        int c0 = 0, c1 = 0, c2 = 0, c3 = 0, tot = 0;
        if (lane < NCB) {
            c0 = lcnt[0][lane]; c1 = lcnt[1][lane];
            c2 = lcnt[2][lane]; c3 = lcnt[3][lane];
            tot = c0 + c1 + c2 + c3;
        }
        const int inc = wave_incl_scan(tot, lane);
        const int ex = inc - tot;
        if (lane < NCB) {
            loffs[lane]    = ex;
            lbase[0][lane] = ex;
            lbase[1][lane] = ex + c0;
            lbase[2][lane] = ex + c0 + c1;
            lbase[3][lane] = ex + c0 + c1 + c2;
            grun[lane] = atomicAdd(&ccursor[lane], tot);
        }
    }
    __syncthreads();

#pragma unroll
    for (int j = 0; j < 8; ++j) {
        const int e = base + j * 256 + tid;
        if (e < NEDGE) {
            const int cb = (int)rv[j] >> 10;
            const int pos = atomicAdd(&lbase[wv][cb], 1);
            lrecm[pos] = rm[j];
            lrecv[pos] = rv[j];
        }
    }
    __syncthreads();

    for (int i = tid; i < n; i += 256) {
        const unsigned int   m = lrecm[i];
        const unsigned short v = lrecv[i];
        const int cb = (int)v >> 10;
        const int dst = grun[cb] + (i - loffs[cb]);
        c8m[dst] = m;
        c8v[dst] = v;
    }
}

// ---------------------------------------------------------------------------
// hist_conv: blocks 0..195 = fine hist (2-byte c8v stream only); blocks
// 196..977 = vrepr f32->bf16x2 conversion (independent of coarse).
// ---------------------------------------------------------------------------
__global__ __launch_bounds__(1024) void hist_conv_kernel(
    const unsigned short* __restrict__ c8v, const int* __restrict__ ccursor,
    int* __restrict__ hcnt,
    const float* __restrict__ vrepr, unsigned int* __restrict__ vrepr16)
{
    __shared__ int cnt[1024];
    const int b = blockIdx.x, tid = threadIdx.x;
    if (b < FINE_BLOCKS) {
        const int bin = b >> 2, s = b & 3;
        const int bs = bin * BSTRIDE;
        const int len = ccursor[bin] - bs;
        const int qs = bs + ((len * s) >> 2);
        const int qe = bs + ((len * (s + 1)) >> 2);
        cnt[tid] = 0;
        __syncthreads();
        for (int i = qs + tid; i < qe; i += 1024)
            atomicAdd(&cnt[c8v[i] & 1023], 1);
        __syncthreads();
        hcnt[b * 1024 + tid] = cnt[tid];
    } else {
        const int gid = (b - FINE_BLOCKS) * 1024 + tid;
        if (gid < (VNUM * OUTF) / 8) {
            const float4 v0 = *reinterpret_cast<const float4*>(vrepr + (size_t)gid * 8);
            const float4 v1 = *reinterpret_cast<const float4*>(vrepr + (size_t)gid * 8 + 4);
            uint4 pk;
            pk.x = (unsigned)f2bf(v0.x) | ((unsigned)f2bf(v0.y) << 16);
            pk.y = (unsigned)f2bf(v0.z) | ((unsigned)f2bf(v0.w) << 16);
            pk.z = (unsigned)f2bf(v1.x) | ((unsigned)f2bf(v1.y) << 16);
            pk.w = (unsigned)f2bf(v1.z) | ((unsigned)f2bf(v1.w) << 16);
            *reinterpret_cast<uint4*>(vrepr16 + (size_t)gid * 4) = pk;
        }
    }
}

// ---------------------------------------------------------------------------
// scatter_fine: wave 0 recomputes the 49-bin packed prefix from ccursor,
// bin-wide scan from 4 hcnt slices, LDS cursors, rank + scatter. R21: NT
// loads of c8m/c8v in the scatter loop (final reads of those buffers).
// ---------------------------------------------------------------------------
__global__ __launch_bounds__(1024) void scatter_fine_kernel(
    const unsigned int* __restrict__ c8m, const unsigned short* __restrict__ c8v,
    const int* __restrict__ ccursor, const int* __restrict__ hcnt,
    int* __restrict__ offs, unsigned int* __restrict__ pairs)
{
    __shared__ int cur[1024];
    __shared__ int wsum[16];
    __shared__ int sh_s0;
    const int tid = threadIdx.x, lane = tid & 63, wv = tid >> 6;
    const int bin = blockIdx.x >> 2, s = blockIdx.x & 3;
    const int bs = bin * BSTRIDE;

    if (tid < 64) {
        const int lenl = (tid < NCB) ? (ccursor[tid] - tid * BSTRIDE) : 0;
        const int incc = wave_incl_scan(lenl, tid);
        if (tid == bin) sh_s0 = incc - lenl;   // packed exclusive prefix
    }

    const int len = ccursor[bin] - bs;
    const int qs = bs + ((len * s) >> 2);
    const int qe = bs + ((len * (s + 1)) >> 2);

    const int c0 = hcnt[(bin * 4 + 0) * 1024 + tid];
    const int c1 = hcnt[(bin * 4 + 1) * 1024 + tid];
    const int c2 = hcnt[(bin * 4 + 2) * 1024 + tid];
    const int c3 = hcnt[(bin * 4 + 3) * 1024 + tid];
    const int tot = c0 + c1 + c2 + c3;
    const int pre = (s > 0 ? c0 : 0) + (s > 1 ? c1 : 0) + (s > 2 ? c2 : 0);

    const int inc = wave_incl_scan(tot, lane);
    if (lane == 63) wsum[wv] = inc;
    __syncthreads();
    if (tid == 0) {
        int run = 0;
        for (int i = 0; i < 16; ++i) { const int t = wsum[i]; wsum[i] = run; run += t; }
    }
    __syncthreads();
    const int ex = sh_s0 + wsum[wv] + inc - tot;   // global offs for vertex gv
    const int gv = (bin << 10) + tid;
    if (s == 0 && gv < VNUM) offs[gv] = ex;
    cur[tid] = ex + pre;
    __syncthreads();

    for (int i = qs + tid; i < qe; i += 1024) {
        const unsigned short v = __builtin_nontemporal_load(c8v + i);
        const unsigned int   m = __builtin_nontemporal_load(c8m + i);
        const int pos = atomicAdd(&cur[(int)v & 1023], 1);
        pairs[pos] = m;
    }
}

// ---------------------------------------------------------------------------
// aggregate: one wave per vertex, lane covers cols (2l, 2l+1). 256 B
// coalesced bf16-row gathers. R21: unroll-16 deep window (R4: 8->12 = +3%;
// VGPR stays < 64 occupancy cliff). CACHED pairs loads (R6/R8-proven) +
// nontemporal PACKED-BF16 store (WRITE 25->12.5MB).
// ---------------------------------------------------------------------------
__global__ __launch_bounds__(256) void aggregate_kernel(
    const int* __restrict__ offs, const unsigned int* __restrict__ pairs,
    const unsigned int* __restrict__ vrepr16, unsigned int* __restrict__ accu)
{
    const int v = blockIdx.x * 4 + (threadIdx.x >> 6);
    const int l = threadIdx.x & 63;
    int i = offs[v];
    const int end = offs[v + 1];

    float a0 = 0.0f, a1 = 0.0f;
    for (; i + 16 <= end; i += 16) {
        unsigned p[16], r[16];
#pragma unroll
        for (int j = 0; j < 16; ++j) p[j] = pairs[i + j];
#pragma unroll
        for (int j = 0; j < 16; ++j) r[j] = vrepr16[(size_t)(p[j] >> 16) * 64 + l];
#pragma unroll
        for (int j = 0; j < 16; ++j) {
            const float w = bf16_lo(p[j]);
            a0 = fmaf(bf16_lo(r[j]), w, a0);
            a1 = fmaf(bf16_hi(r[j]), w, a1);
        }
    }
    for (; i + 4 <= end; i += 4) {
        unsigned p[4], r[4];
#pragma unroll
        for (int j = 0; j < 4; ++j) p[j] = pairs[i + j];
#pragma unroll
        for (int j = 0; j < 4; ++j) r[j] = vrepr16[(size_t)(p[j] >> 16) * 64 + l];
#pragma unroll
        for (int j = 0; j < 4; ++j) {
            const float w = bf16_lo(p[j]);
            a0 = fmaf(bf16_lo(r[j]), w, a0);
            a1 = fmaf(bf16_hi(r[j]), w, a1);
        }
    }
    for (; i < end; ++i) {
        const unsigned p = pairs[i];
        const unsigned r = vrepr16[(size_t)(p >> 16) * 64 + l];
        const float w = bf16_lo(p);
        a0 = fmaf(bf16_lo(r), w, a0); a1 = fmaf(bf16_hi(r), w, a1);
    }
    const unsigned pk = (unsigned)f2bf(a0) | ((unsigned)f2bf(a1) << 16);
    __builtin_nontemporal_store(pk, accu + (size_t)v * 128 + l);
}

// ---------------------------------------------------------------------------
// gemm via MFMA 16x16x32 bf16. R21: NT load of accu (read-once; keeps L2
// for out writes). In-place safe: block reads exactly the acc16 region of
// the rows it overwrites.
// ---------------------------------------------------------------------------
__global__ __launch_bounds__(256) void gemm_mfma_kernel(
    const unsigned int* accu, const unsigned int* __restrict__ bfrag,
    const float* __restrict__ loc_b, const float* __restrict__ std_b,
    float* out)
{
    __shared__ unsigned short tile[16][136];   // bf16, padded
    const int t = threadIdx.x;
    const int row0 = blockIdx.x * 16;
    const int l = t & 63, w = t >> 6;

    short8 bfr[4][4];
#pragma unroll
    for (int ct = 0; ct < 4; ++ct)
#pragma unroll
        for (int ks = 0; ks < 4; ++ks)
            bfr[ct][ks] = *reinterpret_cast<const short8*>(
                bfrag + ((((w * 4 + ct) * 4 + ks) * 64 + l) << 2));

    {
        const unsigned int* src = accu + (size_t)(row0 + (t >> 4)) * 128 + (t & 15) * 4;
        uint4 av;
        av.x = __builtin_nontemporal_load(src);
        av.y = __builtin_nontemporal_load(src + 1);
        av.z = __builtin_nontemporal_load(src + 2);
        av.w = __builtin_nontemporal_load(src + 3);
        *reinterpret_cast<uint4*>(&tile[t >> 4][(t & 15) * 8]) = av;
    }
    __syncthreads();

    const int m = l & 15, q = l >> 4;
    v4f accv[4];
#pragma unroll
    for (int ct = 0; ct < 4; ++ct) accv[ct] = (v4f){0.0f, 0.0f, 0.0f, 0.0f};

#pragma unroll
    for (int ks = 0; ks < 4; ++ks) {
        const short8 a = *reinterpret_cast<const short8*>(&tile[m][ks * 32 + q * 8]);
#pragma unroll
        for (int ct = 0; ct < 4; ++ct)
            accv[ct] = __builtin_amdgcn_mfma_f32_16x16x32_bf16(
                a, bfr[ct][ks], accv[ct], 0, 0, 0);
    }

#pragma unroll
    for (int ct = 0; ct < 4; ++ct) {
        const int colg = (w * 4 + ct) * 16 + m;
        const int h = colg >> 7, c = colg & 127;
        const float bias = (h ? std_b : loc_b)[c];
        float* dst = out + (h ? (size_t)VNUM * OUTF : (size_t)0);
#pragma unroll
        for (int reg = 0; reg < 4; ++reg) {
            const int row = row0 + q * 4 + reg;
            float x = accv[ct][reg] + bias;
            if (h) x = fmaxf(x, 0.0f) + log1pf(expf(-fabsf(x))) + EPSF;
            dst[(size_t)row * OUTF + c] = x;
        }
    }
}

// Fallback gemm (no workspace): f32 vector path, unpacks bf16 acc.
__global__ __launch_bounds__(256) void gemm_fallback_kernel(
    const unsigned int* accu,
    const float* __restrict__ loc_w, const float* __restrict__ loc_b,
    const float* __restrict__ std_w, const float* __restrict__ std_b,
    float* out)
{
    __shared__ float tile[16][OUTF];
    const int t = threadIdx.x;
    const int row0 = blockIdx.x * 16;
    {
        const uint4 av = *reinterpret_cast<const uint4*>(
            accu + (size_t)(row0 + (t >> 4)) * 128 + (t & 15) * 4);
        float* dst = &tile[t >> 4][(t & 15) * 8];
        dst[0] = bf16_lo(av.x); dst[1] = bf16_hi(av.x);
        dst[2] = bf16_lo(av.y); dst[3] = bf16_hi(av.y);
        dst[4] = bf16_lo(av.z); dst[5] = bf16_hi(av.z);
        dst[6] = bf16_lo(av.w); dst[7] = bf16_hi(av.w);
    }
    __syncthreads();
    const int is_std = t >> 7;
    const int c = t & 127;
    const float* w = (is_std ? std_w : loc_w) + (size_t)c * OUTF;
    const float bias = is_std ? std_b[c] : loc_b[c];
    float accv[16];
#pragma unroll
    for (int r = 0; r < 16; ++r) accv[r] = 0.0f;
    for (int k = 0; k < OUTF; k += 4) {
        const float4 wv = *reinterpret_cast<const float4*>(w + k);
#pragma unroll
        for (int r = 0; r < 16; ++r) {
            const float4 pv = *reinterpret_cast<const float4*>(&tile[r][k]);
            float a = accv[r];
            a = fmaf(pv.x, wv.x, a); a = fmaf(pv.y, wv.y, a);
            a = fmaf(pv.z, wv.z, a); a = fmaf(pv.w, wv.w, a);
            accv[r] = a;
        }
    }
    float* dst_base = out + (is_std ? (size_t)VNUM * OUTF : (size_t)0);
#pragma unroll
    for (int r = 0; r < 16; ++r) {
        const float x = accv[r] + bias;
        dst_base[(size_t)(row0 + r) * OUTF + c] =
            is_std ? (fmaxf(x, 0.0f) + log1pf(expf(-fabsf(x))) + EPSF) : x;
    }
}

extern "C" void kernel_launch(void* const* d_in, const int* in_sizes, int n_in,
                              void* d_out, int out_size, void* d_ws, size_t ws_size,
                              hipStream_t stream) {
    const int*   sidx  = (const int*)  d_in[0];
    const int*   tidx  = (const int*)  d_in[1];
    const float* enorm = (const float*)d_in[2];
    const float* esgn  = (const float*)d_in[3];
    const float* vrepr = (const float*)d_in[4];
    const float* loc_w = (const float*)d_in[5];
    const float* loc_b = (const float*)d_in[6];
    const float* std_w = (const float*)d_in[7];
    const float* std_b = (const float*)d_in[8];

    float* out = (float*)d_out;

    // Loc half: c8m (1.806M uints, 7.2MB) + c8v (1.806M ushorts, 3.6MB) —
    // dead after scatter_fine. Then loc half holds acc16 (packed bf16,
    // identity-strided: row v -> uints [v*128, v*128+64)).
    unsigned int*   c8m  = (unsigned int*)out;
    unsigned short* c8v  = (unsigned short*)(c8m + (size_t)NCB * BSTRIDE);
    unsigned int*   accu = (unsigned int*)out;

    // std-half scratch layout (~5.05M of 6.4M words):
    //   pairs 1.6M | vrepr16 3.2M | offs 50001 | ccursor 49 | hcnt 196*1024
    unsigned int* sbase   = (unsigned int*)(out + (size_t)VNUM * OUTF);
    unsigned int* pairs   = sbase;
    unsigned int* vrepr16 = sbase + NEDGE;
    int* offs    = (int*)(sbase + NEDGE + (size_t)VNUM * 64);
    int* ccursor = offs + VNUM + 1;
    int* hcnt    = ccursor + NCB;

    const bool use_ws = ws_size >= 16384 * sizeof(unsigned int);  // 64 KB
    unsigned int* bfrag = use_ws ? (unsigned int*)d_ws : nullptr;

    const int prep_blocks = 1 + (use_ws ? BFRAG_BLOCKS : 0);
    prep_kernel        <<<prep_blocks, 256, 0, stream>>>(ccursor, offs,
                                                         loc_w, std_w, bfrag);
    coarse_kernel      <<<COARSE_BLOCKS, 256, 0, stream>>>(sidx, tidx, enorm, esgn,
                                                           ccursor, c8m, c8v);
    hist_conv_kernel   <<<FINE_BLOCKS + CONV_BLOCKS, 1024, 0, stream>>>(
                            c8v, ccursor, hcnt, vrepr, vrepr16);
    scatter_fine_kernel<<<FINE_BLOCKS, 1024, 0, stream>>>(c8m, c8v, ccursor, hcnt,
                                                          offs, pairs);
    aggregate_kernel   <<<VNUM / 4, 256, 0, stream>>>(offs, pairs, vrepr16, accu);

    if (use_ws) {
        gemm_mfma_kernel<<<VNUM / 16, 256, 0, stream>>>(accu, bfrag, loc_b, std_b, out);
    } else {
        gemm_fallback_kernel<<<VNUM / 16, 256, 0, stream>>>(accu, loc_w, loc_b,
                                                            std_w, std_b, out);
    }
}

// Round 23
// 225.079 us; speedup vs baseline: 1.0502x; 1.0502x over previous
//
#include <hip/hip_runtime.h>
#include <math.h>

#define VNUM 50000
#define OUTF 128
#define NEDGE 1600000
#define EPSF 1e-7f

#define BFRAG_BLOCKS 64     // 16384 uint pairs / 256

#define CHUNK 2048          // edges per coarse block
#define NCB 49              // coarse bins: tidx>>10 (1024 vertices/bin)
#define COARSE_BLOCKS 782   // ceil(NEDGE/CHUNK)
#define BSTRIDE 36864       // fixed segment stride; mean 32768 + 23 sigma
#define NSUB 4              // sub-blocks per bin (R8: 8 = +6.5us; R10 coop = +35us; R15 LDS-fuse = +1300us)
#define FINE_BLOCKS (NCB * NSUB)   // 196
#define CONV_BLOCKS 782     // conversion blocks @1024 thr

typedef __attribute__((ext_vector_type(8))) short short8;
typedef __attribute__((ext_vector_type(4))) float v4f;

// ---------------------------------------------------------------------------
// bf16 helpers (RNE)
// ---------------------------------------------------------------------------
__device__ __forceinline__ unsigned short f2bf(float f) {
    union { float f; unsigned int u; } c; c.f = f;
    unsigned int u = c.u;
    return (unsigned short)((u + 0x7FFFu + ((u >> 16) & 1u)) >> 16);
}
__device__ __forceinline__ float bf16_lo(unsigned int p) {
    union { unsigned int u; float f; } c; c.u = p << 16; return c.f;
}
__device__ __forceinline__ float bf16_hi(unsigned int p) {
    union { unsigned int u; float f; } c; c.u = p & 0xFFFF0000u; return c.f;
}

__device__ __forceinline__ int wave_incl_scan(int v, int lane) {
#pragma unroll
    for (int off = 1; off < 64; off <<= 1) {
        const int o = __shfl_up(v, off, 64);
        if (lane >= off) v += o;
    }
    return v;
}

// ---------------------------------------------------------------------------
// prep: block 0 = ccursor init + offs[VNUM]; blocks 1..64 = B-fragment build.
// ---------------------------------------------------------------------------
__global__ __launch_bounds__(256) void prep_kernel(
    int* __restrict__ ccursor, int* __restrict__ offs,
    const float* __restrict__ loc_w, const float* __restrict__ std_w,
    unsigned int* bfrag)
{
    const int b = blockIdx.x, tid = threadIdx.x;
    if (b == 0) {
        if (tid < NCB) ccursor[tid] = tid * BSTRIDE;
        if (tid == 63) offs[VNUM] = NEDGE;
    } else {
        const int p = (b - 1) * 256 + tid; // 0..16383
        const int j2 = p & 3, lq = (p >> 2) & 63, ks = (p >> 8) & 3, ct = p >> 10;
        const int k = ks * 32 + (lq >> 4) * 8 + j2 * 2;
        const int n = ct * 16 + (lq & 15);
        const float* wsrc = (n >> 7) ? std_w : loc_w;
        const int c = n & 127;
        bfrag[p] = (unsigned)f2bf(wsrc[c * 128 + k]) |
                   ((unsigned)f2bf(wsrc[c * 128 + k + 1]) << 16);
    }
}

// ---------------------------------------------------------------------------
// coarse: 49 fixed-stride bin segments via LDS staging + bulk-reserved runs.
// 6-byte records — c8m = uint {sidx<<16|bf16(w)}, c8v = ushort tidx.
// CACHED loads (R22: NT loads on edge streams cost +10us — reverted).
// ---------------------------------------------------------------------------
__global__ __launch_bounds__(256) void coarse_kernel(
    const int* __restrict__ sidx, const int* __restrict__ tidx,
    const float* __restrict__ enorm, const float* __restrict__ esgn,
    int* __restrict__ ccursor,
    unsigned int* __restrict__ c8m, unsigned short* __restrict__ c8v)
{
    __shared__ unsigned int   lrecm[CHUNK];   // 8 KB
    __shared__ unsigned short lrecv[CHUNK];   // 4 KB
    __shared__ int lcnt[4][NCB];
    __shared__ int lbase[4][NCB];
    __shared__ int loffs[NCB];
    __shared__ int grun[NCB];

    const int tid = threadIdx.x, lane = tid & 63, wv = tid >> 6;
    const int base = blockIdx.x * CHUNK;
    const int n = min(CHUNK, NEDGE - base);

    for (int i = tid; i < 4 * NCB; i += 256) (&lcnt[0][0])[i] = 0;
    __syncthreads();

    unsigned int rm[8];
    unsigned short rv[8];
#pragma unroll
    for (int j = 0; j < 8; ++j) {
        const int e = base + j * 256 + tid;
        if (e < NEDGE) {
            const int t = tidx[e];
            const float w = esgn[e] * enorm[e];
            rm[j] = ((unsigned)sidx[e] << 16) | (unsigned)f2bf(w);
            rv[j] = (unsigned short)t;
            atomicAdd(&lcnt[wv][t >> 10], 1);
        }
    }
    __syncthreads();

    if (tid < 64) {
        int c0 = 0, c1 = 0, c2 = 0, c3 = 0, tot = 0;
        if (lane < NCB) {
            c0 = lcnt[0][lane]; c1 = lcnt[1][lane];
            c2 = lcnt[2][lane]; c3 = lcnt[3][lane];
            tot = c0 + c1 + c2 + c3;
        }
        const int inc = wave_incl_scan(tot, lane);
        const int ex = inc - tot;
        if (lane < NCB) {
            loffs[lane]    = ex;
            lbase[0][lane] = ex;
            lbase[1][lane] = ex + c0;
            lbase[2][lane] = ex + c0 + c1;
            lbase[3][lane] = ex + c0 + c1 + c2;
            grun[lane] = atomicAdd(&ccursor[lane], tot);
        }
    }
    __syncthreads();

#pragma unroll
    for (int j = 0; j < 8; ++j) {
        const int e = base + j * 256 + tid;
        if (e < NEDGE) {
            const int cb = (int)rv[j] >> 10;
            const int pos = atomicAdd(&lbase[wv][cb], 1);
            lrecm[pos] = rm[j];
            lrecv[pos] = rv[j];
        }
    }
    __syncthreads();

    for (int i = tid; i < n; i += 256) {
        const unsigned int   m = lrecm[i];
        const unsigned short v = lrecv[i];
        const int cb = (int)v >> 10;
        const int dst = grun[cb] + (i - loffs[cb]);
        c8m[dst] = m;
        c8v[dst] = v;
    }
}

// ---------------------------------------------------------------------------
// hist_conv: blocks 0..195 = fine hist (2-byte c8v stream only); blocks
// 196..977 = vrepr f32->bf16x2 conversion (independent of coarse).
// ---------------------------------------------------------------------------
__global__ __launch_bounds__(1024) void hist_conv_kernel(
    const unsigned short* __restrict__ c8v, const int* __restrict__ ccursor,
    int* __restrict__ hcnt,
    const float* __restrict__ vrepr, unsigned int* __restrict__ vrepr16)
{
    __shared__ int cnt[1024];
    const int b = blockIdx.x, tid = threadIdx.x;
    if (b < FINE_BLOCKS) {
        const int bin = b >> 2, s = b & 3;
        const int bs = bin * BSTRIDE;
        const int len = ccursor[bin] - bs;
        const int qs = bs + ((len * s) >> 2);
        const int qe = bs + ((len * (s + 1)) >> 2);
        cnt[tid] = 0;
        __syncthreads();
        for (int i = qs + tid; i < qe; i += 1024)
            atomicAdd(&cnt[c8v[i] & 1023], 1);
        __syncthreads();
        hcnt[b * 1024 + tid] = cnt[tid];
    } else {
        const int gid = (b - FINE_BLOCKS) * 1024 + tid;
        if (gid < (VNUM * OUTF) / 8) {
            const float4 v0 = *reinterpret_cast<const float4*>(vrepr + (size_t)gid * 8);
            const float4 v1 = *reinterpret_cast<const float4*>(vrepr + (size_t)gid * 8 + 4);
            uint4 pk;
            pk.x = (unsigned)f2bf(v0.x) | ((unsigned)f2bf(v0.y) << 16);
            pk.y = (unsigned)f2bf(v0.z) | ((unsigned)f2bf(v0.w) << 16);
            pk.z = (unsigned)f2bf(v1.x) | ((unsigned)f2bf(v1.y) << 16);
            pk.w = (unsigned)f2bf(v1.z) | ((unsigned)f2bf(v1.w) << 16);
            *reinterpret_cast<uint4*>(vrepr16 + (size_t)gid * 4) = pk;
        }
    }
}

// ---------------------------------------------------------------------------
// scatter_fine: wave 0 recomputes the 49-bin packed prefix from ccursor,
// bin-wide scan from 4 hcnt slices, LDS cursors, rank + scatter.
// CACHED c8 loads (R22 NT revert).
// ---------------------------------------------------------------------------
__global__ __launch_bounds__(1024) void scatter_fine_kernel(
    const unsigned int* __restrict__ c8m, const unsigned short* __restrict__ c8v,
    const int* __restrict__ ccursor, const int* __restrict__ hcnt,
    int* __restrict__ offs, unsigned int* __restrict__ pairs)
{
    __shared__ int cur[1024];
    __shared__ int wsum[16];
    __shared__ int sh_s0;
    const int tid = threadIdx.x, lane = tid & 63, wv = tid >> 6;
    const int bin = blockIdx.x >> 2, s = blockIdx.x & 3;
    const int bs = bin * BSTRIDE;

    if (tid < 64) {
        const int lenl = (tid < NCB) ? (ccursor[tid] - tid * BSTRIDE) : 0;
        const int incc = wave_incl_scan(lenl, tid);
        if (tid == bin) sh_s0 = incc - lenl;   // packed exclusive prefix
    }

    const int len = ccursor[bin] - bs;
    const int qs = bs + ((len * s) >> 2);
    const int qe = bs + ((len * (s + 1)) >> 2);

    const int c0 = hcnt[(bin * 4 + 0) * 1024 + tid];
    const int c1 = hcnt[(bin * 4 + 1) * 1024 + tid];
    const int c2 = hcnt[(bin * 4 + 2) * 1024 + tid];
    const int c3 = hcnt[(bin * 4 + 3) * 1024 + tid];
    const int tot = c0 + c1 + c2 + c3;
    const int pre = (s > 0 ? c0 : 0) + (s > 1 ? c1 : 0) + (s > 2 ? c2 : 0);

    const int inc = wave_incl_scan(tot, lane);
    if (lane == 63) wsum[wv] = inc;
    __syncthreads();
    if (tid == 0) {
        int run = 0;
        for (int i = 0; i < 16; ++i) { const int t = wsum[i]; wsum[i] = run; run += t; }
    }
    __syncthreads();
    const int ex = sh_s0 + wsum[wv] + inc - tot;   // global offs for vertex gv
    const int gv = (bin << 10) + tid;
    if (s == 0 && gv < VNUM) offs[gv] = ex;
    cur[tid] = ex + pre;
    __syncthreads();

    for (int i = qs + tid; i < qe; i += 1024) {
        const unsigned short v = c8v[i];
        const int pos = atomicAdd(&cur[(int)v & 1023], 1);
        pairs[pos] = c8m[i];
    }
}

// ---------------------------------------------------------------------------
// aggregate (R11/R21-proven): one wave per vertex, lane covers cols
// (2l, 2l+1). 256 B coalesced bf16-row gathers, unroll-12, CACHED pairs
// loads + nontemporal PACKED-BF16 store (WRITE 25->12.5MB).
// ---------------------------------------------------------------------------
__global__ __launch_bounds__(256) void aggregate_kernel(
    const int* __restrict__ offs, const unsigned int* __restrict__ pairs,
    const unsigned int* __restrict__ vrepr16, unsigned int* __restrict__ accu)
{
    const int v = blockIdx.x * 4 + (threadIdx.x >> 6);
    const int l = threadIdx.x & 63;
    int i = offs[v];
    const int end = offs[v + 1];

    float a0 = 0.0f, a1 = 0.0f;
    for (; i + 12 <= end; i += 12) {
        unsigned p[12], r[12];
#pragma unroll
        for (int j = 0; j < 12; ++j) p[j] = pairs[i + j];
#pragma unroll
        for (int j = 0; j < 12; ++j) r[j] = vrepr16[(size_t)(p[j] >> 16) * 64 + l];
#pragma unroll
        for (int j = 0; j < 12; ++j) {
            const float w = bf16_lo(p[j]);
            a0 = fmaf(bf16_lo(r[j]), w, a0);
            a1 = fmaf(bf16_hi(r[j]), w, a1);
        }
    }
    for (; i + 4 <= end; i += 4) {
        unsigned p[4], r[4];
#pragma unroll
        for (int j = 0; j < 4; ++j) p[j] = pairs[i + j];
#pragma unroll
        for (int j = 0; j < 4; ++j) r[j] = vrepr16[(size_t)(p[j] >> 16) * 64 + l];
#pragma unroll
        for (int j = 0; j < 4; ++j) {
            const float w = bf16_lo(p[j]);
            a0 = fmaf(bf16_lo(r[j]), w, a0);
            a1 = fmaf(bf16_hi(r[j]), w, a1);
        }
    }
    for (; i < end; ++i) {
        const unsigned p = pairs[i];
        const unsigned r = vrepr16[(size_t)(p >> 16) * 64 + l];
        const float w = bf16_lo(p);
        a0 = fmaf(bf16_lo(r), w, a0); a1 = fmaf(bf16_hi(r), w, a1);
    }
    const unsigned pk = (unsigned)f2bf(a0) | ((unsigned)f2bf(a1) << 16);
    __builtin_nontemporal_store(pk, accu + (size_t)v * 128 + l);
}

// ---------------------------------------------------------------------------
// gemm via MFMA 16x16x32 bf16 (cached accu load — R22 NT revert). In-place
// safe: block reads exactly the acc16 region of the rows it overwrites.
// ---------------------------------------------------------------------------
__global__ __launch_bounds__(256) void gemm_mfma_kernel(
    const unsigned int* accu, const unsigned int* __restrict__ bfrag,
    const float* __restrict__ loc_b, const float* __restrict__ std_b,
    float* out)
{
    __shared__ unsigned short tile[16][136];   // bf16, padded
    const int t = threadIdx.x;
    const int row0 = blockIdx.x * 16;
    const int l = t & 63, w = t >> 6;

    short8 bfr[4][4];
#pragma unroll
    for (int ct = 0; ct < 4; ++ct)
#pragma unroll
        for (int ks = 0; ks < 4; ++ks)
            bfr[ct][ks] = *reinterpret_cast<const short8*>(
                bfrag + ((((w * 4 + ct) * 4 + ks) * 64 + l) << 2));

    {
        const uint4 av = *reinterpret_cast<const uint4*>(
            accu + (size_t)(row0 + (t >> 4)) * 128 + (t & 15) * 4);
        *reinterpret_cast<uint4*>(&tile[t >> 4][(t & 15) * 8]) = av;
    }
    __syncthreads();

    const int m = l & 15, q = l >> 4;
    v4f accv[4];
#pragma unroll
    for (int ct = 0; ct < 4; ++ct) accv[ct] = (v4f){0.0f, 0.0f, 0.0f, 0.0f};

#pragma unroll
    for (int ks = 0; ks < 4; ++ks) {
        const short8 a = *reinterpret_cast<const short8*>(&tile[m][ks * 32 + q * 8]);
#pragma unroll
        for (int ct = 0; ct < 4; ++ct)
            accv[ct] = __builtin_amdgcn_mfma_f32_16x16x32_bf16(
                a, bfr[ct][ks], accv[ct], 0, 0, 0);
    }

#pragma unroll
    for (int ct = 0; ct < 4; ++ct) {
        const int colg = (w * 4 + ct) * 16 + m;
        const int h = colg >> 7, c = colg & 127;
        const float bias = (h ? std_b : loc_b)[c];
        float* dst = out + (h ? (size_t)VNUM * OUTF : (size_t)0);
#pragma unroll
        for (int reg = 0; reg < 4; ++reg) {
            const int row = row0 + q * 4 + reg;
            float x = accv[ct][reg] + bias;
            if (h) x = fmaxf(x, 0.0f) + log1pf(expf(-fabsf(x))) + EPSF;
            dst[(size_t)row * OUTF + c] = x;
        }
    }
}

// Fallback gemm (no workspace): f32 vector path, unpacks bf16 acc.
__global__ __launch_bounds__(256) void gemm_fallback_kernel(
    const unsigned int* accu,
    const float* __restrict__ loc_w, const float* __restrict__ loc_b,
    const float* __restrict__ std_w, const float* __restrict__ std_b,
    float* out)
{
    __shared__ float tile[16][OUTF];
    const int t = threadIdx.x;
    const int row0 = blockIdx.x * 16;
    {
        const uint4 av = *reinterpret_cast<const uint4*>(
            accu + (size_t)(row0 + (t >> 4)) * 128 + (t & 15) * 4);
        float* dst = &tile[t >> 4][(t & 15) * 8];
        dst[0] = bf16_lo(av.x); dst[1] = bf16_hi(av.x);
        dst[2] = bf16_lo(av.y); dst[3] = bf16_hi(av.y);
        dst[4] = bf16_lo(av.z); dst[5] = bf16_hi(av.z);
        dst[6] = bf16_lo(av.w); dst[7] = bf16_hi(av.w);
    }
    __syncthreads();
    const int is_std = t >> 7;
    const int c = t & 127;
    const float* w = (is_std ? std_w : loc_w) + (size_t)c * OUTF;
    const float bias = is_std ? std_b[c] : loc_b[c];
    float accv[16];
#pragma unroll
    for (int r = 0; r < 16; ++r) accv[r] = 0.0f;
    for (int k = 0; k < OUTF; k += 4) {
        const float4 wv = *reinterpret_cast<const float4*>(w + k);
#pragma unroll
        for (int r = 0; r < 16; ++r) {
            const float4 pv = *reinterpret_cast<const float4*>(&tile[r][k]);
            float a = accv[r];
            a = fmaf(pv.x, wv.x, a); a = fmaf(pv.y, wv.y, a);
            a = fmaf(pv.z, wv.z, a); a = fmaf(pv.w, wv.w, a);
            accv[r] = a;
        }
    }
    float* dst_base = out + (is_std ? (size_t)VNUM * OUTF : (size_t)0);
#pragma unroll
    for (int r = 0; r < 16; ++r) {
        const float x = accv[r] + bias;
        dst_base[(size_t)(row0 + r) * OUTF + c] =
            is_std ? (fmaxf(x, 0.0f) + log1pf(expf(-fabsf(x))) + EPSF) : x;
    }
}

extern "C" void kernel_launch(void* const* d_in, const int* in_sizes, int n_in,
                              void* d_out, int out_size, void* d_ws, size_t ws_size,
                              hipStream_t stream) {
    const int*   sidx  = (const int*)  d_in[0];
    const int*   tidx  = (const int*)  d_in[1];
    const float* enorm = (const float*)d_in[2];
    const float* esgn  = (const float*)d_in[3];
    const float* vrepr = (const float*)d_in[4];
    const float* loc_w = (const float*)d_in[5];
    const float* loc_b = (const float*)d_in[6];
    const float* std_w = (const float*)d_in[7];
    const float* std_b = (const float*)d_in[8];

    float* out = (float*)d_out;

    // Loc half: c8m (1.806M uints, 7.2MB) + c8v (1.806M ushorts, 3.6MB) —
    // dead after scatter_fine. Then loc half holds acc16 (packed bf16,
    // identity-strided: row v -> uints [v*128, v*128+64)).
    unsigned int*   c8m  = (unsigned int*)out;
    unsigned short* c8v  = (unsigned short*)(c8m + (size_t)NCB * BSTRIDE);
    unsigned int*   accu = (unsigned int*)out;

    // std-half scratch layout (~5.05M of 6.4M words):
    //   pairs 1.6M | vrepr16 3.2M | offs 50001 | ccursor 49 | hcnt 196*1024
    unsigned int* sbase   = (unsigned int*)(out + (size_t)VNUM * OUTF);
    unsigned int* pairs   = sbase;
    unsigned int* vrepr16 = sbase + NEDGE;
    int* offs    = (int*)(sbase + NEDGE + (size_t)VNUM * 64);
    int* ccursor = offs + VNUM + 1;
    int* hcnt    = ccursor + NCB;

    const bool use_ws = ws_size >= 16384 * sizeof(unsigned int);  // 64 KB
    unsigned int* bfrag = use_ws ? (unsigned int*)d_ws : nullptr;

    const int prep_blocks = 1 + (use_ws ? BFRAG_BLOCKS : 0);
    prep_kernel        <<<prep_blocks, 256, 0, stream>>>(ccursor, offs,
                                                         loc_w, std_w, bfrag);
    coarse_kernel      <<<COARSE_BLOCKS, 256, 0, stream>>>(sidx, tidx, enorm, esgn,
                                                           ccursor, c8m, c8v);
    hist_conv_kernel   <<<FINE_BLOCKS + CONV_BLOCKS, 1024, 0, stream>>>(
                            c8v, ccursor, hcnt, vrepr, vrepr16);
    scatter_fine_kernel<<<FINE_BLOCKS, 1024, 0, stream>>>(c8m, c8v, ccursor, hcnt,
                                                          offs, pairs);
    aggregate_kernel   <<<VNUM / 4, 256, 0, stream>>>(offs, pairs, vrepr16, accu);

    if (use_ws) {
        gemm_mfma_kernel<<<VNUM / 16, 256, 0, stream>>>(accu, bfrag, loc_b, std_b, out);
    } else {
        gemm_fallback_kernel<<<VNUM / 16, 256, 0, stream>>>(accu, loc_w, loc_b,
                                                            std_w, std_b, out);
    }
}